// Round 6
// baseline (196.779 us; speedup 1.0000x reference)
//
#include <hip/hip_runtime.h>
#include <hip/hip_bf16.h>

// Problem constants (fixed by setup_inputs)
constexpr int B  = 16;
constexpr int N  = 4096;
constexpr int NP = 1024;
constexpr int C  = 64;
constexpr int NS = 32;            // nsample
constexpr int OC = C + 3;         // output channels = 67
constexpr float R2 = 0.2f * 0.2f; // radius^2

typedef float v4f __attribute__((ext_vector_type(4)));
typedef int   v4i __attribute__((ext_vector_type(4)));

// ---------------------------------------------------------------------------
// Kernel 1 (fused): blocks [0,1024) transpose points[b,c,n] -> pointsT[b,n,c];
// blocks [1024,5120) do ball query (one wave per center, 128 pts/iter).
// Transpose blocks first so their HBM traffic starts immediately and overlaps
// the VALU-bound ball query.
// ---------------------------------------------------------------------------
__global__ __launch_bounds__(256)
void prep_kernel(const float* __restrict__ xyz,
                 const float* __restrict__ new_xyz,
                 const float* __restrict__ points,
                 float* __restrict__ out,
                 int* __restrict__ ws_idx,
                 float* __restrict__ pointsT)
{
    __shared__ float tile[64][65];

    if (blockIdx.x < 1024) {
        // ---- transpose: 64x64 tile per block ----
        const int tb  = blockIdx.x;
        const int b   = tb >> 6;          // batch
        const int n0  = (tb & 63) << 6;   // n-tile origin
        const int col = threadIdx.x & 63;
        const int r0  = (threadIdx.x >> 6) << 4; // 16 rows per wave-group

        const float* src = points + (size_t)b * C * N + n0;
        #pragma unroll
        for (int k = 0; k < 16; ++k) {
            const int c = r0 + k;
            tile[c][col] = src[(size_t)c * N + col]; // coalesced along n
        }
        __syncthreads();
        float* dst = pointsT + (size_t)b * N * C + (size_t)n0 * C;
        #pragma unroll
        for (int k = 0; k < 16; ++k) {
            const int n = r0 + k;
            dst[(size_t)n * C + col] = tile[col][n]; // coalesced along c
        }
        return;
    }

    // ---- ball query: one wave per center ----
    const int wid  = ((blockIdx.x - 1024) << 2) + (threadIdx.x >> 6);
    const int lane = threadIdx.x & 63;
    const int b = wid >> 10;
    const int p = wid & (NP - 1);

    const float qx = new_xyz[wid * 3 + 0];
    const float qy = new_xyz[wid * 3 + 1];
    const float qz = new_xyz[wid * 3 + 2];

    const float* xb = xyz + (size_t)b * N * 3;

    float* out_x = out + (((size_t)b * OC + 0) * NP + p) * NS;
    float* out_y = out + (((size_t)b * OC + 1) * NP + p) * NS;
    float* out_z = out + (((size_t)b * OC + 2) * NP + p) * NS;
    int*   idx_p = ws_idx + (size_t)wid * NS;

    // defaults: reference fills with index 0 when no point is in radius
    float fdx = xb[0] - qx;
    float fdy = xb[1] - qy;
    float fdz = xb[2] - qz;
    int   fidx = 0;

    int cnt = 0;
    for (int base = 0; base < N && cnt < NS; base += 128) {
        const int j0 = base + lane;
        const int j1 = base + 64 + lane;

        const float x0 = xb[j0 * 3 + 0];
        const float y0 = xb[j0 * 3 + 1];
        const float z0 = xb[j0 * 3 + 2];
        const float x1 = xb[j1 * 3 + 0];
        const float y1 = xb[j1 * 3 + 1];
        const float z1 = xb[j1 * 3 + 2];

        const float dx0 = x0 - qx, dy0 = y0 - qy, dz0 = z0 - qz;
        const float dx1 = x1 - qx, dy1 = y1 - qy, dz1 = z1 - qz;
        // match numpy float32: ((dx*dx)+(dy*dy))+(dz*dz), block FMA fusion
        const float d20 = __fadd_rn(__fadd_rn(__fmul_rn(dx0, dx0),
                                              __fmul_rn(dy0, dy0)),
                                    __fmul_rn(dz0, dz0));
        const float d21 = __fadd_rn(__fadd_rn(__fmul_rn(dx1, dx1),
                                              __fmul_rn(dy1, dy1)),
                                    __fmul_rn(dz1, dz1));
        const bool in0 = d20 < R2;
        const bool in1 = d21 < R2;
        const unsigned long long m0 = __ballot(in0);
        const unsigned long long m1 = __ballot(in1);

        if (cnt == 0) {
            if (m0 != 0ull) {
                const int fl = __ffsll(m0) - 1;
                fdx = __shfl(dx0, fl, 64);
                fdy = __shfl(dy0, fl, 64);
                fdz = __shfl(dz0, fl, 64);
                fidx = base + fl;
            } else if (m1 != 0ull) {
                const int fl = __ffsll(m1) - 1;
                fdx = __shfl(dx1, fl, 64);
                fdy = __shfl(dy1, fl, 64);
                fdz = __shfl(dz1, fl, 64);
                fidx = base + 64 + fl;
            }
        }

        const unsigned long long below = (1ull << lane) - 1ull;
        if (in0) {
            const int slot = cnt + (int)__popcll(m0 & below);
            if (slot < NS) {
                idx_p[slot] = j0;
                out_x[slot] = dx0;
                out_y[slot] = dy0;
                out_z[slot] = dz0;
            }
        }
        const int c0 = cnt + (int)__popcll(m0);
        if (in1) {
            const int slot = c0 + (int)__popcll(m1 & below);
            if (slot < NS) {
                idx_p[slot] = j1;
                out_x[slot] = dx1;
                out_y[slot] = dy1;
                out_z[slot] = dz1;
            }
        }
        cnt = c0 + (int)__popcll(m1);
    }

    const int cntc = cnt < NS ? cnt : NS;
    if (lane >= cntc && lane < NS) {
        idx_p[lane] = fidx;
        out_x[lane] = fdx;
        out_y[lane] = fdy;
        out_z[lane] = fdz;
    }
}

// ---------------------------------------------------------------------------
// Kernel 2: gather. One WAVE per center (lane = channel). 32 coalesced 256 B
// row loads from pointsT (L2-pinned via batch->XCD swizzle), per-wave LDS
// transpose (2-way bank aliasing only = free), 32 coalesced nt-stores.
// No __syncthreads: each wave owns its LDS slice.
// ---------------------------------------------------------------------------
__global__ __launch_bounds__(256)
void gather_kernel(const float* __restrict__ pointsT,
                   const int* __restrict__ ws_idx,
                   float* __restrict__ out)
{
    __shared__ float sbuf[4][NS * 65]; // 4 waves x 8.3 KB = 33.3 KB

    const int g    = blockIdx.x;            // 4096 blocks
    const int b    = g & 15;                // batch -> XCD = b%8 (L2 locality)
    const int wave = threadIdx.x >> 6;
    const int lane = threadIdx.x & 63;
    const int p    = ((g >> 4) << 2) + wave;

    float* sb = &sbuf[wave][0];
    const int* idx_p = ws_idx + ((size_t)b * NP + p) * NS;
    const int myidx = (lane < NS) ? idx_p[lane] : 0;

    const float* rb = pointsT + (size_t)b * N * C;

    float vals[NS];
    #pragma unroll
    for (int s = 0; s < NS; ++s) {
        const int rn = __shfl(myidx, s, 64);       // wave-uniform row index
        vals[s] = rb[(size_t)rn * C + lane];       // coalesced 256 B row
    }
    #pragma unroll
    for (int s = 0; s < NS; ++s)
        sb[s * 65 + lane] = vals[s];               // (s+c)%32 -> 2-way, free

    const int s    = lane & 31;
    const int half = lane >> 5;
    float* ob = out + ((size_t)b * OC + 3) * NP * NS + (size_t)p * NS;
    #pragma unroll
    for (int j = 0; j < 32; ++j) {
        const int c = 2 * j + half;
        const float v = sb[s * 65 + c];            // (s+c)%32 -> 2-way, free
        __builtin_nontemporal_store(v, ob + (size_t)c * NP * NS + s);
    }
}

extern "C" void kernel_launch(void* const* d_in, const int* in_sizes, int n_in,
                              void* d_out, int out_size, void* d_ws, size_t ws_size,
                              hipStream_t stream)
{
    const float* xyz     = (const float*)d_in[0]; // (B, N, 3)
    const float* new_xyz = (const float*)d_in[1]; // (B, NP, 3)
    const float* points  = (const float*)d_in[2]; // (B, C, N)
    float* out = (float*)d_out;                   // (B, 67, NP, NS)

    int*   ws_idx  = (int*)d_ws;                                // 2 MB
    float* pointsT = (float*)((char*)d_ws + ((size_t)2 << 20)); // 64 MB (B,N,C)

    // blocks [0,1024): transpose; blocks [1024,5120): ball query
    prep_kernel<<<1024 + (B * NP) / 4, 256, 0, stream>>>(
        xyz, new_xyz, points, out, ws_idx, pointsT);

    // one wave per center, batch pinned to XCD via g&15
    gather_kernel<<<(B * NP) / 4, 256, 0, stream>>>(pointsT, ws_idx, out);
}

// Round 7
// 196.042 us; speedup vs baseline: 1.0038x; 1.0038x over previous
//
#include <hip/hip_runtime.h>
#include <hip/hip_bf16.h>

// Problem constants (fixed by setup_inputs)
constexpr int B  = 16;
constexpr int N  = 4096;
constexpr int NP = 1024;
constexpr int C  = 64;
constexpr int NS = 32;            // nsample
constexpr int OC = C + 3;         // output channels = 67
constexpr float R2 = 0.2f * 0.2f; // radius^2

constexpr int TPAD = 36;          // sbT row stride (x4B = 144 B, 16B-aligned)

typedef float v4f __attribute__((ext_vector_type(4)));

// ---------------------------------------------------------------------------
// Kernel 1: transpose points[b,c,n] -> pointsT[b,n,c]  (16.8 MB each way)
// ---------------------------------------------------------------------------
__global__ __launch_bounds__(256)
void transpose_kernel(const float* __restrict__ points,
                      float* __restrict__ pointsT)
{
    __shared__ float tile[64][65];

    const int tb  = blockIdx.x;       // 1024 blocks
    const int b   = tb >> 6;
    const int n0  = (tb & 63) << 6;
    const int col = threadIdx.x & 63;
    const int r0  = (threadIdx.x >> 6) << 4;

    const float* src = points + (size_t)b * C * N + n0;
    #pragma unroll
    for (int k = 0; k < 16; ++k) {
        const int c = r0 + k;
        tile[c][col] = src[(size_t)c * N + col]; // coalesced along n
    }
    __syncthreads();
    float* dst = pointsT + (size_t)b * N * C + (size_t)n0 * C;
    #pragma unroll
    for (int k = 0; k < 16; ++k) {
        const int n = r0 + k;
        dst[(size_t)n * C + col] = tile[col][n]; // coalesced along c
    }
}

// ---------------------------------------------------------------------------
// Kernel 2 (fused): one WAVE per center.
//  Phase 1: ball query (128 pts/iter, ordered ballots) -> idx/dx/dy/dz in LDS
//  Phase 2: write grouped_xyz coalesced; gather pointsT rows (256 B coalesced,
//           L2-pinned via b = blockIdx&15 -> XCD), LDS transpose with b128
//           write/read (structurally conflict-free), 4x-vectorized nt stores.
// No __syncthreads anywhere: every LDS slice is wave-private.
// ---------------------------------------------------------------------------
__global__ __launch_bounds__(256)
void query_gather_kernel(const float* __restrict__ xyz,
                         const float* __restrict__ new_xyz,
                         const float* __restrict__ pointsT,
                         float* __restrict__ out)
{
    __shared__ __align__(16) float sbT[4][C * TPAD]; // 4 x 9.2 KB
    __shared__ int   sidx[4][NS];
    __shared__ float sdx[4][NS], sdy[4][NS], sdz[4][NS];

    const int g    = blockIdx.x;        // 4096 blocks
    const int b    = g & 15;            // batch -> XCD = g%8 (2 batches/XCD)
    const int wave = threadIdx.x >> 6;
    const int lane = threadIdx.x & 63;
    const int p    = ((g >> 4) << 2) + wave;
    const int wid  = (b << 10) + p;     // center id = b*NP + p

    const float qx = new_xyz[wid * 3 + 0];
    const float qy = new_xyz[wid * 3 + 1];
    const float qz = new_xyz[wid * 3 + 2];

    const float* xb = xyz + (size_t)b * N * 3;

    // defaults: reference fills with index 0 when no point is in radius
    float fdx = xb[0] - qx;
    float fdy = xb[1] - qy;
    float fdz = xb[2] - qz;
    int   fidx = 0;

    int* wi = sidx[wave];
    float *wx = sdx[wave], *wy = sdy[wave], *wz = sdz[wave];

    int cnt = 0;
    for (int base = 0; base < N && cnt < NS; base += 128) {
        const int j0 = base + lane;
        const int j1 = base + 64 + lane;

        const float x0 = xb[j0 * 3 + 0];
        const float y0 = xb[j0 * 3 + 1];
        const float z0 = xb[j0 * 3 + 2];
        const float x1 = xb[j1 * 3 + 0];
        const float y1 = xb[j1 * 3 + 1];
        const float z1 = xb[j1 * 3 + 2];

        const float dx0 = x0 - qx, dy0 = y0 - qy, dz0 = z0 - qz;
        const float dx1 = x1 - qx, dy1 = y1 - qy, dz1 = z1 - qz;
        // match numpy float32: ((dx*dx)+(dy*dy))+(dz*dz), block FMA fusion
        const float d20 = __fadd_rn(__fadd_rn(__fmul_rn(dx0, dx0),
                                              __fmul_rn(dy0, dy0)),
                                    __fmul_rn(dz0, dz0));
        const float d21 = __fadd_rn(__fadd_rn(__fmul_rn(dx1, dx1),
                                              __fmul_rn(dy1, dy1)),
                                    __fmul_rn(dz1, dz1));
        const bool in0 = d20 < R2;
        const bool in1 = d21 < R2;
        const unsigned long long m0 = __ballot(in0);
        const unsigned long long m1 = __ballot(in1);

        if (cnt == 0) {
            if (m0 != 0ull) {
                const int fl = __ffsll(m0) - 1;
                fdx = __shfl(dx0, fl, 64);
                fdy = __shfl(dy0, fl, 64);
                fdz = __shfl(dz0, fl, 64);
                fidx = base + fl;
            } else if (m1 != 0ull) {
                const int fl = __ffsll(m1) - 1;
                fdx = __shfl(dx1, fl, 64);
                fdy = __shfl(dy1, fl, 64);
                fdz = __shfl(dz1, fl, 64);
                fidx = base + 64 + fl;
            }
        }

        const unsigned long long below = (1ull << lane) - 1ull;
        if (in0) {
            const int slot = cnt + (int)__popcll(m0 & below);
            if (slot < NS) {
                wi[slot] = j0; wx[slot] = dx0; wy[slot] = dy0; wz[slot] = dz0;
            }
        }
        const int c0 = cnt + (int)__popcll(m0);
        if (in1) {
            const int slot = c0 + (int)__popcll(m1 & below);
            if (slot < NS) {
                wi[slot] = j1; wx[slot] = dx1; wy[slot] = dy1; wz[slot] = dz1;
            }
        }
        cnt = c0 + (int)__popcll(m1);
    }

    const int cntc = cnt < NS ? cnt : NS;
    if (lane >= cntc && lane < NS) {
        wi[lane] = fidx; wx[lane] = fdx; wy[lane] = fdy; wz[lane] = fdz;
    }

    // grouped_xyz: 3 coalesced 128 B stores
    const size_t obase = ((size_t)b * OC) * NP * NS + (size_t)p * NS;
    if (lane < NS) {
        __builtin_nontemporal_store(wx[lane], out + obase + lane);
        __builtin_nontemporal_store(wy[lane], out + obase + (size_t)NP * NS + lane);
        __builtin_nontemporal_store(wz[lane], out + obase + (size_t)2 * NP * NS + lane);
    }

    // ---- gather phase: lane = channel ----
    const int myidx = wi[lane & 31];
    const float* rb = pointsT + (size_t)b * N * C;
    float* sT = &sbT[wave][0];

    #pragma unroll
    for (int s4 = 0; s4 < 8; ++s4) {
        v4f v;
        #pragma unroll
        for (int j = 0; j < 4; ++j) {
            const int s  = (s4 << 2) + j;
            const int rn = __shfl(myidx, s, 64);      // wave-uniform row
            v[j] = rb[(size_t)rn * C + lane];         // coalesced 256 B row
        }
        // b128 write: 8-lane groups cover all 32 banks -> conflict-free
        *(v4f*)&sT[lane * TPAD + (s4 << 2)] = v;
    }

    float* ob = out + obase + (size_t)3 * NP * NS;
    #pragma unroll
    for (int k = 0; k < 8; ++k) {
        const int q  = (k << 6) + lane;   // chunk id in [0, 512)
        const int c  = q >> 3;
        const int s4 = q & 7;
        const v4f v = *(const v4f*)&sT[c * TPAD + (s4 << 2)];
        __builtin_nontemporal_store(v, (v4f*)(ob + (size_t)c * NP * NS + (s4 << 2)));
    }
}

extern "C" void kernel_launch(void* const* d_in, const int* in_sizes, int n_in,
                              void* d_out, int out_size, void* d_ws, size_t ws_size,
                              hipStream_t stream)
{
    const float* xyz     = (const float*)d_in[0]; // (B, N, 3)
    const float* new_xyz = (const float*)d_in[1]; // (B, NP, 3)
    const float* points  = (const float*)d_in[2]; // (B, C, N)
    float* out = (float*)d_out;                   // (B, 67, NP, NS)

    float* pointsT = (float*)d_ws;                // (B, N, C) = 16.8 MB

    transpose_kernel<<<B * (N / 64), 256, 0, stream>>>(points, pointsT);

    // one wave per center, batch pinned to XCD via g&15
    query_gather_kernel<<<(B * NP) / 4, 256, 0, stream>>>(
        xyz, new_xyz, pointsT, out);
}